// Round 5
// baseline (175.074 us; speedup 1.0000x reference)
//
#include <hip/hip_runtime.h>
#include <math.h>

// YOLOv3 decode: x[16, 3, 85, 76, 76] f32 -> out[48, 5776, 85] f32.
// LDS tile in OUTPUT layout, math at LDS-write time (round 3 structure), plus:
//   - persistent blocks: NT=3 consecutive tiles each (grid 1456 = 4368/3)
//   - register prefetch of tile i+1 issued before tile i's math
//   - raw "s_waitcnt lgkmcnt(0); s_barrier" (no vmcnt drain) so prefetch
//     global loads stay in flight across phase 2 (T3/T4 pattern)
// Memory floor: ~150 MB HBM traffic / 6.3 TB/s ~ 24 us.

#define NCH          85
#define SPATIAL      5776      // 76*76
#define GWID         76
#define TS           64
#define TILES_PER_NA 91        // 90 full + 1 tail (rem=16)
#define TOTAL_TILES  (TILES_PER_NA * 48)   // 4368
#define NT           3
#define NBLOCKS      (TOTAL_TILES / NT)    // 1456 exact

__device__ __forceinline__ float fast_sigmoid(float v) {
    return __builtin_amdgcn_rcpf(1.0f + __expf(-v));
}

__device__ __forceinline__ void process4(float* __restrict__ tile,
                                         int c, int sl, int s0,
                                         float4 v, float aw, float ah) {
    float vv[4] = {v.x, v.y, v.z, v.w};
    if (c >= 4) {
        #pragma unroll
        for (int jj = 0; jj < 4; ++jj)
            tile[(sl + jj) * NCH + c] = fast_sigmoid(vv[jj]);
    } else if (c == 0) {
        #pragma unroll
        for (int jj = 0; jj < 4; ++jj) {
            const int sg = s0 + sl + jj;
            tile[(sl + jj) * NCH + c] =
                (fast_sigmoid(vv[jj]) + (float)(sg % GWID)) * (1.0f / GWID);
        }
    } else if (c == 1) {
        #pragma unroll
        for (int jj = 0; jj < 4; ++jj) {
            const int sg = s0 + sl + jj;
            tile[(sl + jj) * NCH + c] =
                (fast_sigmoid(vv[jj]) + (float)(sg / GWID)) * (1.0f / GWID);
        }
    } else if (c == 2) {
        #pragma unroll
        for (int jj = 0; jj < 4; ++jj)
            tile[(sl + jj) * NCH + c] = __expf(vv[jj]) * aw;
    } else {   // c == 3
        #pragma unroll
        for (int jj = 0; jj < 4; ++jj)
            tile[(sl + jj) * NCH + c] = __expf(vv[jj]) * ah;
    }
}

// issue 6 independent dwordx4 loads for a FULL tile (rem==64)
#define LOAD_FULL(tid, A0, A1, A2, A3, A4, A5)                                 \
    do {                                                                       \
        const int na_ = (tid) / TILES_PER_NA;                                  \
        const int j_  = (tid) - na_ * TILES_PER_NA;                            \
        const float* p_ = x + (size_t)na_ * NCH * SPATIAL + j_ * TS            \
                            + cbase * SPATIAL + sl;                            \
        A0 = *reinterpret_cast<const float4*>(p_);                             \
        A1 = *reinterpret_cast<const float4*>(p_ + 16 * SPATIAL);              \
        A2 = *reinterpret_cast<const float4*>(p_ + 32 * SPATIAL);              \
        A3 = *reinterpret_cast<const float4*>(p_ + 48 * SPATIAL);              \
        A4 = *reinterpret_cast<const float4*>(p_ + 64 * SPATIAL);              \
        if (extra)                                                             \
            A5 = *reinterpret_cast<const float4*>(p_ + (80 - cbase + cbase + 64 + 16 - 64) * SPATIAL + (80 + cbase - cbase - 16) * SPATIAL); \
    } while (0)
// NOTE: A5 expression simplified below in code (kept explicit there).

#define LDS_BAR() asm volatile("s_waitcnt lgkmcnt(0)\n\ts_barrier" ::: "memory")

__global__ __launch_bounds__(256, 5) void yolo_decode(
    const float* __restrict__ x,
    const float* __restrict__ anchors,
    float* __restrict__ out)
{
    __shared__ __align__(16) float tile[NCH * TS];   // 21760 B

    const int t     = threadIdx.x;
    const int sl    = (t & 15) << 2;   // spatial-in-tile *4 (full-tile mapping)
    const int cbase = t >> 4;          // 0..15
    const bool extra = (t < 80);       // lanes covering c = 80..84

    int tid = blockIdx.x * NT;

    float4 R0, R1, R2, R3, R4, R5;
    float4 N0, N1, N2, N3, N4, N5;

    bool pf_cur = ((tid % TILES_PER_NA) != TILES_PER_NA - 1);
    if (pf_cur) {
        const int na_ = tid / TILES_PER_NA;
        const int j_  = tid - na_ * TILES_PER_NA;
        const float* p_ = x + (size_t)na_ * NCH * SPATIAL + j_ * TS
                            + cbase * SPATIAL + sl;
        R0 = *reinterpret_cast<const float4*>(p_);
        R1 = *reinterpret_cast<const float4*>(p_ + 16 * SPATIAL);
        R2 = *reinterpret_cast<const float4*>(p_ + 32 * SPATIAL);
        R3 = *reinterpret_cast<const float4*>(p_ + 48 * SPATIAL);
        R4 = *reinterpret_cast<const float4*>(p_ + 64 * SPATIAL);
        if (extra)
            R5 = *reinterpret_cast<const float4*>(p_ + (80 - cbase) * SPATIAL
                                                     + cbase * SPATIAL);
        // (80 - cbase + cbase) = 80: loads channel 80 + cbase via p_ math:
        // p_ already includes cbase*SPATIAL, so offset (80-cbase)*SPATIAL + cbase*SPATIAL
        // == 80*SPATIAL from in_base + cbase*SPATIAL -> channel 80+cbase. Wait:
        // p_ = in_base + cbase*SPATIAL + sl; adding 80*SPATIAL gives channel cbase+80. OK.
    }

    #pragma unroll 1
    for (int i = 0; i < NT; ++i, ++tid) {
        const int na = tid / TILES_PER_NA;
        const int j  = tid - na * TILES_PER_NA;
        const int s0 = j * TS;
        const int a  = na % 3;
        const float aw = anchors[2 * a]     * (1.0f / 608.0f);
        const float ah = anchors[2 * a + 1] * (1.0f / 608.0f);
        const float* in_base = x + (size_t)na * NCH * SPATIAL + s0;
        float* out_base = out + ((size_t)na * SPATIAL + s0) * NCH;

        // ---- prefetch tile i+1 (issued before consuming current regs) ----
        const bool pf_next = (i + 1 < NT) &&
                             (((tid + 1) % TILES_PER_NA) != TILES_PER_NA - 1);
        if (pf_next) {
            const int na_ = (tid + 1) / TILES_PER_NA;
            const int j_  = (tid + 1) - na_ * TILES_PER_NA;
            const float* p_ = x + (size_t)na_ * NCH * SPATIAL + j_ * TS
                                + cbase * SPATIAL + sl;
            N0 = *reinterpret_cast<const float4*>(p_);
            N1 = *reinterpret_cast<const float4*>(p_ + 16 * SPATIAL);
            N2 = *reinterpret_cast<const float4*>(p_ + 32 * SPATIAL);
            N3 = *reinterpret_cast<const float4*>(p_ + 48 * SPATIAL);
            N4 = *reinterpret_cast<const float4*>(p_ + 64 * SPATIAL);
            if (extra)
                N5 = *reinterpret_cast<const float4*>(p_ + 80 * SPATIAL);
        }

        if (pf_cur) {
            // ---- full tile: math + LDS scatter from prefetched regs ----
            process4(tile, cbase +  0, sl, s0, R0, aw, ah);
            process4(tile, cbase + 16, sl, s0, R1, aw, ah);
            process4(tile, cbase + 32, sl, s0, R2, aw, ah);
            process4(tile, cbase + 48, sl, s0, R3, aw, ah);
            process4(tile, cbase + 64, sl, s0, R4, aw, ah);
            if (extra)
                process4(tile, cbase + 80, sl, s0, R5, aw, ah);

            LDS_BAR();   // lgkm only: prefetch global loads stay in flight

            // ---- phase 2: linear b128 reads + contiguous stores ----
            const int fb = t << 2;
            float4 o0 = *reinterpret_cast<const float4*>(&tile[fb]);
            float4 o1 = *reinterpret_cast<const float4*>(&tile[fb + 1024]);
            float4 o2 = *reinterpret_cast<const float4*>(&tile[fb + 2048]);
            float4 o3 = *reinterpret_cast<const float4*>(&tile[fb + 3072]);
            float4 o4 = *reinterpret_cast<const float4*>(&tile[fb + 4096]);
            *reinterpret_cast<float4*>(out_base + fb)        = o0;
            *reinterpret_cast<float4*>(out_base + fb + 1024) = o1;
            *reinterpret_cast<float4*>(out_base + fb + 2048) = o2;
            *reinterpret_cast<float4*>(out_base + fb + 3072) = o3;
            *reinterpret_cast<float4*>(out_base + fb + 4096) = o4;
            if (extra) {
                const int fbt = 5120 + (t << 2);
                float4 ot = *reinterpret_cast<const float4*>(&tile[fbt]);
                *reinterpret_cast<float4*>(out_base + fbt) = ot;
            }

            LDS_BAR();   // protect LDS reuse next iteration
        } else {
            // ---- tail tile (rem = 16): simple synchronous path ----
            const int rem = SPATIAL - s0;           // 16
            for (int idx = t; idx < NCH * (rem / 4); idx += 256) {
                const int c   = idx >> 2;
                const int slx = (idx & 3) << 2;
                const float4 v = *reinterpret_cast<const float4*>(
                    in_base + c * SPATIAL + slx);
                process4(tile, c, slx, s0, v, aw, ah);
            }
            __syncthreads();
            const int nv4 = (NCH * rem) >> 2;       // 340
            for (int v = t; v < nv4; v += 256) {
                const float4 o = *reinterpret_cast<const float4*>(&tile[v << 2]);
                *reinterpret_cast<float4*>(out_base + (v << 2)) = o;
            }
            __syncthreads();
        }

        R0 = N0; R1 = N1; R2 = N2; R3 = N3; R4 = N4; R5 = N5;
        pf_cur = pf_next;
    }
}

extern "C" void kernel_launch(void* const* d_in, const int* in_sizes, int n_in,
                              void* d_out, int out_size, void* d_ws, size_t ws_size,
                              hipStream_t stream) {
    const float* x       = (const float*)d_in[0];
    const float* anchors = (const float*)d_in[1];
    float* out           = (float*)d_out;

    yolo_decode<<<dim3(NBLOCKS), 256, 0, stream>>>(x, anchors, out);
}

// Round 7
// 169.529 us; speedup vs baseline: 1.0327x; 1.0327x over previous
//
#include <hip/hip_runtime.h>
#include <math.h>

// YOLOv3 decode: x[16, 3, 85, 76, 76] f32 -> out[48, 5776, 85] f32.
// Round 6: TS=152 (= 2*76), 512 threads.
//   - 38 tiles per (n,a) slice EXACTLY -> no tail path at all
//   - reads ~608B contiguous per half-wave (vs 256B before)
//   - LDS 51.7KB output-layout tile -> 3 blocks/CU, 24 waves/CU
//   - s0 % 76 == 0 -> gx/gy computed without division
// Memory floor: ~150 MB HBM traffic / 6.3 TB/s ~ 24 us.

#define NCH     85
#define SPATIAL 5776          // 76*76
#define GW      76
#define TS      152           // 2*76
#define NTILES  38            // 5776 / 152 exactly
#define NF4     (NCH * TS / 4)   // 3230 float4 per tile
#define EXTRA_T (NF4 - 512 * 6)  // 158: threads doing a 7th item

__device__ __forceinline__ float fast_sigmoid(float v) {
    return __builtin_amdgcn_rcpf(1.0f + __expf(-v));
}

// one float4 worth of math + scatter into output-layout LDS tile
__device__ __forceinline__ void scatter4(float* __restrict__ tile,
                                         int c, int k, int j2,
                                         float4 v, float aw, float ah) {
    float vv[4] = {v.x, v.y, v.z, v.w};
    #pragma unroll
    for (int jj = 0; jj < 4; ++jj) {
        const int pos = 4 * k + jj;          // 0..151 spatial within tile
        float r;
        if (c == 0) {
            const int gx = (pos < GW) ? pos : pos - GW;   // sg % 76
            r = (fast_sigmoid(vv[jj]) + (float)gx) * (1.0f / GW);
        } else if (c == 1) {
            const int gy = j2 + ((pos >= GW) ? 1 : 0);    // sg / 76
            r = (fast_sigmoid(vv[jj]) + (float)gy) * (1.0f / GW);
        } else if (c == 2) {
            r = __expf(vv[jj]) * aw;
        } else if (c == 3) {
            r = __expf(vv[jj]) * ah;
        } else {
            r = fast_sigmoid(vv[jj]);
        }
        tile[pos * NCH + c] = r;
    }
}

__global__ __launch_bounds__(512) void yolo_decode(
    const float* __restrict__ x,
    const float* __restrict__ anchors,
    float* __restrict__ out)
{
    __shared__ __align__(16) float tile[NCH * TS];   // 51680 B -> 3 blocks/CU

    const int j  = blockIdx.x;          // 0..37 tile within slice
    const int na = blockIdx.y;          // 0..47  (n*3 + a)
    const int a  = na % 3;
    const int s0 = j * TS;
    const int t  = threadIdx.x;
    const int j2 = 2 * j;               // gy base (s0 / 76)

    const float aw = anchors[2 * a]     * (1.0f / 608.0f);
    const float ah = anchors[2 * a + 1] * (1.0f / 608.0f);

    const float* in_base = x + (size_t)na * NCH * SPATIAL + s0;
    float* out_base = out + ((size_t)na * SPATIAL + s0) * NCH;  // 16B aligned

    // f4 index m = t + 512*i  ->  channel c = m/38, col k = m%38
    int c[7], k[7];
    #pragma unroll
    for (int i = 0; i < 7; ++i) {
        const int m = t + 512 * i;
        c[i] = m / 38;                  // magic-mul div (compile-time divisor)
        k[i] = m - 38 * c[i];
    }
    const bool extra = (t < EXTRA_T);   // t < 158

    // ---- phase 1: issue ALL 6-7 independent loads, then math + scatter ----
    float4 v0 = *reinterpret_cast<const float4*>(in_base + c[0] * SPATIAL + 4 * k[0]);
    float4 v1 = *reinterpret_cast<const float4*>(in_base + c[1] * SPATIAL + 4 * k[1]);
    float4 v2 = *reinterpret_cast<const float4*>(in_base + c[2] * SPATIAL + 4 * k[2]);
    float4 v3 = *reinterpret_cast<const float4*>(in_base + c[3] * SPATIAL + 4 * k[3]);
    float4 v4 = *reinterpret_cast<const float4*>(in_base + c[4] * SPATIAL + 4 * k[4]);
    float4 v5 = *reinterpret_cast<const float4*>(in_base + c[5] * SPATIAL + 4 * k[5]);
    float4 v6;
    if (extra)
        v6 = *reinterpret_cast<const float4*>(in_base + c[6] * SPATIAL + 4 * k[6]);

    scatter4(tile, c[0], k[0], j2, v0, aw, ah);
    scatter4(tile, c[1], k[1], j2, v1, aw, ah);
    scatter4(tile, c[2], k[2], j2, v2, aw, ah);
    scatter4(tile, c[3], k[3], j2, v3, aw, ah);
    scatter4(tile, c[4], k[4], j2, v4, aw, ah);
    scatter4(tile, c[5], k[5], j2, v5, aw, ah);
    if (extra)
        scatter4(tile, c[6], k[6], j2, v6, aw, ah);

    __syncthreads();

    // ---- phase 2: LDS already output-layout; linear b128 reads + stores ----
    #pragma unroll
    for (int i = 0; i < 6; ++i) {
        const int m = t + 512 * i;
        const float4 o = *reinterpret_cast<const float4*>(&tile[4 * m]);
        *reinterpret_cast<float4*>(out_base + 4 * m) = o;
    }
    if (extra) {
        const int m = t + 512 * 6;
        const float4 o = *reinterpret_cast<const float4*>(&tile[4 * m]);
        *reinterpret_cast<float4*>(out_base + 4 * m) = o;
    }
}

extern "C" void kernel_launch(void* const* d_in, const int* in_sizes, int n_in,
                              void* d_out, int out_size, void* d_ws, size_t ws_size,
                              hipStream_t stream) {
    const float* x       = (const float*)d_in[0];
    const float* anchors = (const float*)d_in[1];
    float* out           = (float*)d_out;

    dim3 grid(NTILES, 48);    // 38 x 48 = 1824 blocks, 512 threads each
    yolo_decode<<<grid, 512, 0, stream>>>(x, anchors, out);
}